// Round 1
// baseline (2534.607 us; speedup 1.0000x reference)
//
#include <hip/hip_runtime.h>
#include <hip/hip_fp16.h>

// Sinkhorn / entropic Wasserstein, N=M=8192, D=32, EPS=10, <=50 iters.
// Strategy: build Ks = 2^14 * exp(-C/EPS) once in fp16 (128 MB, L3-resident),
// then alternate row/col matvec sweeps. Scale 2^14 is Sinkhorn-invariant.
// Early-stop emulated via deterministic err partials in ws; converged
// iterations become ~no-op launches (data-dependent, same launches each call).

#define NN 8192
#define DDIM 32
#define EPSF 10.0f
#define LOG2E 1.44269504088896340736f
#define LN2F 0.69314718055994530942f
#define KLOG2 14.0f          // Ks = 2^14 * K
#define THRESH2 1e-10f       // (1e-5)^2

// ---- workspace layout (bytes) ----
#define OFF_KS   0ull                       // 8192*8192 fp16 = 134217728
#define OFF_PART (134217728ull)             // 128*8192 fp32  = 4194304
#define OFF_A    (OFF_PART + 4194304ull)    // 8192 fp32
#define OFF_B    (OFF_A + 32768ull)         // 8192 fp32
#define OFF_X2   (OFF_B + 32768ull)         // 8192 fp32
#define OFF_Y2   (OFF_X2 + 32768ull)        // 8192 fp32
#define OFF_B16  (OFF_Y2 + 32768ull)        // 8192 fp16
#define OFF_ERR  (OFF_B16 + 16384ull)       // 32 fp32 err partials
#define WS_NEEDED (OFF_ERR + 4096ull)       // ~132.1 MB

__device__ __forceinline__ bool is_done(const float* __restrict__ errpart) {
    float e = 0.f;
#pragma unroll
    for (int k = 0; k < 32; ++k) e += errpart[k];
    return e < THRESH2;
}

// ---- init: x2, y2 row norms; b=1; errpart=big; out[0]=0 ----
__global__ __launch_bounds__(256) void k_init(const float* __restrict__ x,
                                              const float* __restrict__ y,
                                              float* __restrict__ x2,
                                              float* __restrict__ y2,
                                              float* __restrict__ b,
                                              __half* __restrict__ b16,
                                              float* __restrict__ errpart,
                                              float* __restrict__ out) {
    int t = blockIdx.x * 256 + threadIdx.x;   // grid 32 -> t in [0,8192)
    const float4* x4 = (const float4*)(x + (size_t)t * DDIM);
    float s = 0.f;
#pragma unroll
    for (int k = 0; k < 8; ++k) { float4 v = x4[k]; s += v.x*v.x + v.y*v.y + v.z*v.z + v.w*v.w; }
    x2[t] = s;
    const float4* y4 = (const float4*)(y + (size_t)t * DDIM);
    s = 0.f;
#pragma unroll
    for (int k = 0; k < 8; ++k) { float4 v = y4[k]; s += v.x*v.x + v.y*v.y + v.z*v.z + v.w*v.w; }
    y2[t] = s;
    b[t] = 1.0f;
    b16[t] = __float2half(1.0f);
    if (t < 32) errpart[t] = 1e30f;
    if (t == 0) out[0] = 0.f;
}

// ---- build Ks: tile 32 rows x 256 cols per WG, grid 8192 ----
__global__ __launch_bounds__(256) void k_build(const float* __restrict__ x,
                                               const float* __restrict__ y,
                                               const float* __restrict__ x2,
                                               const float* __restrict__ y2,
                                               __half* __restrict__ Ks) {
    __shared__ float yT[DDIM][256];          // [d][col] 32 KB
    __shared__ float xT[DDIM][32];           // [d][row]  4 KB
    __shared__ __align__(16) __half hb[32][256]; // bounce 16 KB
    const int t = threadIdx.x;
    const int jb = blockIdx.x & 31;          // 32 col blocks of 256
    const int ib = blockIdx.x >> 5;          // 256 row blocks of 32
    const int colbase = jb * 256, rowbase = ib * 32;

    // y tile -> transposed LDS (per-lane 128B contiguous global reads)
    {
        const float4* yp = (const float4*)(y + (size_t)(colbase + t) * DDIM);
#pragma unroll
        for (int k = 0; k < 8; ++k) {
            float4 v = yp[k];
            yT[4*k+0][t] = v.x; yT[4*k+1][t] = v.y; yT[4*k+2][t] = v.z; yT[4*k+3][t] = v.w;
        }
    }
    // x tile -> transposed LDS
    {
        int r = t >> 3, ds = (t & 7) * 4;
        float4 v = *(const float4*)(x + (size_t)(rowbase + r) * DDIM + ds);
        xT[ds+0][r] = v.x; xT[ds+1][r] = v.y; xT[ds+2][r] = v.z; xT[ds+3][r] = v.w;
    }
    __syncthreads();

    float acc[32];
#pragma unroll
    for (int r = 0; r < 32; ++r) acc[r] = 0.f;
    for (int d = 0; d < DDIM; ++d) {
        float yv = yT[d][t];                 // conflict-free (lane-consecutive)
#pragma unroll
        for (int r4 = 0; r4 < 8; ++r4) {     // uniform b128 broadcast reads
            float4 xv = *(const float4*)&xT[d][r4 * 4];
            acc[r4*4+0] = fmaf(xv.x, yv, acc[r4*4+0]);
            acc[r4*4+1] = fmaf(xv.y, yv, acc[r4*4+1]);
            acc[r4*4+2] = fmaf(xv.z, yv, acc[r4*4+2]);
            acc[r4*4+3] = fmaf(xv.w, yv, acc[r4*4+3]);
        }
    }
    const float y2c = y2[colbase + t];
#pragma unroll
    for (int r = 0; r < 32; ++r) {
        float Cv = fmaxf(x2[rowbase + r] + y2c - 2.f * acc[r], 0.f);
        float arg = KLOG2 - Cv * (LOG2E / EPSF);
        hb[r][t] = __float2half(__builtin_amdgcn_exp2f(arg));
    }
    __syncthreads();
    // coalesced store: 32 rows x 512B via LDS bounce
#pragma unroll
    for (int u = 0; u < 4; ++u) {
        int id = u * 256 + t;
        int r = id >> 5, seg = id & 31;
        uint4 v = *(const uint4*)&hb[r][seg * 8];
        *(uint4*)&Ks[(size_t)(rowbase + r) * NN + colbase + seg * 8] = v;
    }
}

// ---- row pass: a[i] = p[i] / sum_j Ks[i][j]*b[j]; one row per wave ----
__global__ __launch_bounds__(256) void k_row(const __half* __restrict__ Ks,
                                             const __half* __restrict__ b16,
                                             const float* __restrict__ p,
                                             float* __restrict__ a,
                                             const float* __restrict__ errpart) {
    if (is_done(errpart)) return;
    __shared__ __align__(16) __half sb[NN];  // 16 KB staged b
    const int t = threadIdx.x;
#pragma unroll
    for (int k = 0; k < 4; ++k)
        ((uint4*)sb)[k * 256 + t] = ((const uint4*)b16)[k * 256 + t];
    __syncthreads();
    const int wave = t >> 6, lane = t & 63;
    const int row = blockIdx.x * 4 + wave;
    const uint4* kp = (const uint4*)(Ks + (size_t)row * NN);
    const uint4* bp = (const uint4*)sb;
    float acc[4] = {0.f, 0.f, 0.f, 0.f};
    for (int k = 0; k < 16; ++k) {
        uint4 kv = kp[k * 64 + lane];
        uint4 bv = bp[k * 64 + lane];
        const __half2* kh = (const __half2*)&kv;
        const __half2* bh = (const __half2*)&bv;
#pragma unroll
        for (int j = 0; j < 4; ++j) {
            float2 kf = __half22float2(kh[j]);
            float2 bf = __half22float2(bh[j]);
            acc[j] = fmaf(kf.x, bf.x, fmaf(kf.y, bf.y, acc[j]));
        }
    }
    float sum = (acc[0] + acc[1]) + (acc[2] + acc[3]);
#pragma unroll
    for (int off = 32; off > 0; off >>= 1) sum += __shfl_down(sum, off, 64);
    if (lane == 0) a[row] = p[row] / sum;
}

// ---- col pass: partial[ib][j] = sum_{i in block} Ks[i][j]*a[i] ----
__global__ __launch_bounds__(512) void k_col(const __half* __restrict__ Ks,
                                             const float* __restrict__ a,
                                             float* __restrict__ part,
                                             const float* __restrict__ errpart) {
    if (is_done(errpart)) return;
    __shared__ float sa[64];
    const int t = threadIdx.x;
    const int jb = blockIdx.x & 1;           // 2 stripes of 4096 cols
    const int ib = blockIdx.x >> 1;          // 128 row blocks of 64
    const int rowbase = ib * 64;
    const size_t colbase = (size_t)jb * 4096 + (size_t)t * 8;
    if (t < 64) sa[t] = a[rowbase + t];
    __syncthreads();
    const uint4* kp = (const uint4*)(Ks + (size_t)rowbase * NN + colbase);
    float acc[8] = {0.f, 0.f, 0.f, 0.f, 0.f, 0.f, 0.f, 0.f};
    for (int i = 0; i < 64; ++i) {
        uint4 kv = kp[(size_t)i * (NN / 8)];
        float av = sa[i];
        const __half2* kh = (const __half2*)&kv;
#pragma unroll
        for (int j = 0; j < 4; ++j) {
            float2 kf = __half22float2(kh[j]);
            acc[2*j+0] = fmaf(kf.x, av, acc[2*j+0]);
            acc[2*j+1] = fmaf(kf.y, av, acc[2*j+1]);
        }
    }
    float4* pp = (float4*)(part + (size_t)ib * NN + colbase);
    pp[0] = make_float4(acc[0], acc[1], acc[2], acc[3]);
    pp[1] = make_float4(acc[4], acc[5], acc[6], acc[7]);
}

// ---- finalize b: b[j] = q[j]/colsum; deterministic err partials ----
__global__ __launch_bounds__(256) void k_div(const float* __restrict__ part,
                                             const float* __restrict__ q,
                                             float* __restrict__ b,
                                             __half* __restrict__ b16,
                                             float* __restrict__ errpart) {
    if (is_done(errpart)) return;            // keep frozen state intact
    const int t = threadIdx.x;
    const int col = blockIdx.x * 256 + t;    // grid 32
    float sum = 0.f;
    for (int ib = 0; ib < 128; ++ib) sum += part[(size_t)ib * NN + col];
    float bn = q[col] / sum;
    float d = bn - b[col];
    b[col] = bn;
    b16[col] = __float2half(bn);
    float e = d * d;
#pragma unroll
    for (int off = 32; off > 0; off >>= 1) e += __shfl_down(e, off, 64);
    __shared__ float red[4];
    if ((t & 63) == 0) red[t >> 6] = e;
    __syncthreads();
    if (t == 0) errpart[blockIdx.x] = (red[0] + red[1]) + (red[2] + red[3]);
}

// ---- final: T = a*Ks*b (scale-invariant), w = sum T*C, C from log2(Ks) ----
__global__ __launch_bounds__(256) void k_final(const __half* __restrict__ Ks,
                                               const float* __restrict__ a,
                                               const float* __restrict__ b,
                                               float* __restrict__ out) {
    const int t = threadIdx.x;
    const int row = blockIdx.x;              // grid 8192
    const float ai = a[row];
    const uint4* kp = (const uint4*)(Ks + (size_t)row * NN);
    float* Trow = out + 1 + (size_t)row * NN;
    float w = 0.f;
    const float c1 = EPSF * LN2F;
#pragma unroll
    for (int k = 0; k < 4; ++k) {
        const int col = k * 2048 + t * 8;
        uint4 kv = kp[k * 256 + t];
        float4 b0 = *(const float4*)(b + col);
        float4 b1 = *(const float4*)(b + col + 4);
        const __half2* kh = (const __half2*)&kv;
        float kf[8], bv[8] = {b0.x, b0.y, b0.z, b0.w, b1.x, b1.y, b1.z, b1.w};
#pragma unroll
        for (int j = 0; j < 4; ++j) {
            float2 f = __half22float2(kh[j]);
            kf[2*j] = f.x; kf[2*j+1] = f.y;
        }
#pragma unroll
        for (int j = 0; j < 8; ++j) {
            float ks = kf[j];
            float Tv = ai * ks * bv[j];
            float Cv = c1 * (KLOG2 - __builtin_amdgcn_logf(fmaxf(ks, 1e-35f)));
            w = fmaf(Tv, Cv, w);
            Trow[col + j] = Tv;              // d_out+1: scalar stores (offset 4B)
        }
    }
#pragma unroll
    for (int off = 32; off > 0; off >>= 1) w += __shfl_down(w, off, 64);
    __shared__ float red[4];
    if ((t & 63) == 0) red[t >> 6] = w;
    __syncthreads();
    if (t == 0) atomicAdd(out, (red[0] + red[1]) + (red[2] + red[3]));
}

extern "C" void kernel_launch(void* const* d_in, const int* in_sizes, int n_in,
                              void* d_out, int out_size, void* d_ws, size_t ws_size,
                              hipStream_t stream) {
    const float* x = (const float*)d_in[0];
    const float* y = (const float*)d_in[1];
    const float* p = (const float*)d_in[2];
    const float* q = (const float*)d_in[3];
    float* out = (float*)d_out;
    if (ws_size < WS_NEEDED) return;         // ws too small: fail loudly (round 2 pivot)
    char* ws = (char*)d_ws;
    __half* Ks = (__half*)(ws + OFF_KS);
    float* part = (float*)(ws + OFF_PART);
    float* a = (float*)(ws + OFF_A);
    float* b = (float*)(ws + OFF_B);
    float* x2 = (float*)(ws + OFF_X2);
    float* y2 = (float*)(ws + OFF_Y2);
    __half* b16 = (__half*)(ws + OFF_B16);
    float* errpart = (float*)(ws + OFF_ERR);

    k_init<<<dim3(32), dim3(256), 0, stream>>>(x, y, x2, y2, b, b16, errpart, out);
    k_build<<<dim3(8192), dim3(256), 0, stream>>>(x, y, x2, y2, Ks);
    for (int it = 0; it < 50; ++it) {
        k_row<<<dim3(2048), dim3(256), 0, stream>>>(Ks, b16, p, a, errpart);
        k_col<<<dim3(256), dim3(512), 0, stream>>>(Ks, a, part, errpart);
        k_div<<<dim3(32), dim3(256), 0, stream>>>(part, q, b, b16, errpart);
    }
    k_final<<<dim3(8192), dim3(256), 0, stream>>>(Ks, a, b, out);
}

// Round 2
// 2076.751 us; speedup vs baseline: 1.2205x; 1.2205x over previous
//
#include <hip/hip_runtime.h>
#include <hip/hip_fp16.h>

// Sinkhorn / entropic Wasserstein, N=M=8192, D=32, EPS=10, <=50 iters.
// R2: Ks = 2^8 * exp(-C/EPS) stored fp8 e4m3 (64 MB). Evidence from R1: loop is
// HBM-byte-bound (5.7 TB/s, all 50 iters active) -> halve K bytes (fp8) and fuse
// row+col sweeps into one kernel where the col pass re-reads the just-fetched
// 8-row sub-band from L2 (2 MB/XCD working set). Gauss-Seidel order preserved:
// col partials use a_new of the band (computed in the same kernel).

#define NN 8192
#define DDIM 32
#define EPSF 10.0f
#define LOG2E 1.44269504088896340736f
#define LN2F 0.69314718055994530942f
#define KLOG2 8.0f           // Ks = 2^8 * K  (max 256 < 448 e4m3 max)
#define THRESH2 1e-10f       // (1e-5)^2

// ---- workspace layout (bytes) ----
#define OFF_KS   0ull                        // 8192*8192 fp8 = 67108864
#define OFF_PART (67108864ull)               // 256*8192 fp32 = 8388608
#define OFF_A    (OFF_PART + 8388608ull)     // 8192 fp32
#define OFF_B    (OFF_A + 32768ull)          // 8192 fp32
#define OFF_X2   (OFF_B + 32768ull)          // 8192 fp32
#define OFF_Y2   (OFF_X2 + 32768ull)         // 8192 fp32
#define OFF_ERR  (OFF_Y2 + 32768ull)         // 256 fp32 err partials
#define WS_NEEDED (OFF_ERR + 4096ull)        // ~75.6 MB

typedef float floatx2 __attribute__((ext_vector_type(2)));

#if __has_builtin(__builtin_amdgcn_cvt_pk_f32_fp8) && __has_builtin(__builtin_amdgcn_cvt_pk_fp8_f32)
#define HW_FP8 1
#else
#define HW_FP8 0
#include <hip/hip_fp8.h>
#endif

__device__ __forceinline__ void fp8x4_to_f32(unsigned int w, float* f) {
#if HW_FP8
    floatx2 lo = __builtin_amdgcn_cvt_pk_f32_fp8((int)w, false);
    floatx2 hi = __builtin_amdgcn_cvt_pk_f32_fp8((int)w, true);
    f[0] = lo.x; f[1] = lo.y; f[2] = hi.x; f[3] = hi.y;
#else
    for (int i = 0; i < 4; ++i) {
        __hip_fp8_e4m3 h; h.__x = (__hip_fp8_storage_t)((w >> (8 * i)) & 0xff);
        f[i] = (float)h;
    }
#endif
}

__device__ __forceinline__ unsigned char f32_to_fp8(float v) {
#if HW_FP8
    return (unsigned char)(__builtin_amdgcn_cvt_pk_fp8_f32(v, v, 0, false) & 0xff);
#else
    __hip_fp8_e4m3 h(v);
    return (unsigned char)h.__x;
#endif
}

__device__ __forceinline__ bool is_done(const float* __restrict__ errpart) {
    float e = 0.f;
    for (int k = 0; k < 256; ++k) e += errpart[k];
    return e < THRESH2;
}

// ---- init: x2, y2 row norms; b=1; errpart=big; out[0]=0 ----
__global__ __launch_bounds__(256) void k_init(const float* __restrict__ x,
                                              const float* __restrict__ y,
                                              float* __restrict__ x2,
                                              float* __restrict__ y2,
                                              float* __restrict__ b,
                                              float* __restrict__ errpart,
                                              float* __restrict__ out) {
    int t = blockIdx.x * 256 + threadIdx.x;   // grid 32 -> t in [0,8192)
    const float4* x4 = (const float4*)(x + (size_t)t * DDIM);
    float s = 0.f;
#pragma unroll
    for (int k = 0; k < 8; ++k) { float4 v = x4[k]; s += v.x*v.x + v.y*v.y + v.z*v.z + v.w*v.w; }
    x2[t] = s;
    const float4* y4 = (const float4*)(y + (size_t)t * DDIM);
    s = 0.f;
#pragma unroll
    for (int k = 0; k < 8; ++k) { float4 v = y4[k]; s += v.x*v.x + v.y*v.y + v.z*v.z + v.w*v.w; }
    y2[t] = s;
    b[t] = 1.0f;
    if (t < 256) errpart[t] = 1e30f;
    if (t == 0) out[0] = 0.f;
}

// ---- build Ks (fp8): tile 32 rows x 256 cols per WG, grid 8192 ----
__global__ __launch_bounds__(256) void k_build(const float* __restrict__ x,
                                               const float* __restrict__ y,
                                               const float* __restrict__ x2,
                                               const float* __restrict__ y2,
                                               unsigned char* __restrict__ Ks) {
    __shared__ float yT[DDIM][256];               // [d][col] 32 KB
    __shared__ float xT[DDIM][32];                // [d][row]  4 KB
    __shared__ __align__(16) unsigned char hb8[32][256]; // bounce 8 KB
    const int t = threadIdx.x;
    const int jb = blockIdx.x & 31;               // 32 col blocks of 256
    const int ib = blockIdx.x >> 5;               // 256 row blocks of 32
    const int colbase = jb * 256, rowbase = ib * 32;

    {
        const float4* yp = (const float4*)(y + (size_t)(colbase + t) * DDIM);
#pragma unroll
        for (int k = 0; k < 8; ++k) {
            float4 v = yp[k];
            yT[4*k+0][t] = v.x; yT[4*k+1][t] = v.y; yT[4*k+2][t] = v.z; yT[4*k+3][t] = v.w;
        }
    }
    {
        int r = t >> 3, ds = (t & 7) * 4;
        float4 v = *(const float4*)(x + (size_t)(rowbase + r) * DDIM + ds);
        xT[ds+0][r] = v.x; xT[ds+1][r] = v.y; xT[ds+2][r] = v.z; xT[ds+3][r] = v.w;
    }
    __syncthreads();

    float acc[32];
#pragma unroll
    for (int r = 0; r < 32; ++r) acc[r] = 0.f;
    for (int d = 0; d < DDIM; ++d) {
        float yv = yT[d][t];
#pragma unroll
        for (int r4 = 0; r4 < 8; ++r4) {
            float4 xv = *(const float4*)&xT[d][r4 * 4];
            acc[r4*4+0] = fmaf(xv.x, yv, acc[r4*4+0]);
            acc[r4*4+1] = fmaf(xv.y, yv, acc[r4*4+1]);
            acc[r4*4+2] = fmaf(xv.z, yv, acc[r4*4+2]);
            acc[r4*4+3] = fmaf(xv.w, yv, acc[r4*4+3]);
        }
    }
    const float y2c = y2[colbase + t];
#pragma unroll
    for (int r = 0; r < 32; ++r) {
        float Cv = fmaxf(x2[rowbase + r] + y2c - 2.f * acc[r], 0.f);
        float arg = KLOG2 - Cv * (LOG2E / EPSF);
        hb8[r][t] = f32_to_fp8(__builtin_amdgcn_exp2f(arg));
    }
    __syncthreads();
    // coalesced store: 32 rows x 256B via LDS bounce; thread u -> 32 B
    {
        int row = t >> 3, off = (t & 7) * 32;
        uint4 v0 = *(const uint4*)&hb8[row][off];
        uint4 v1 = *(const uint4*)&hb8[row][off + 16];
        unsigned char* dst = Ks + (size_t)(rowbase + row) * NN + colbase + off;
        *(uint4*)dst = v0;
        *(uint4*)(dst + 16) = v1;
    }
}

// ---- fused iteration: per WG a 32-row band; row pass then L2-hot col pass ----
__global__ __launch_bounds__(1024) void k_iter(const unsigned char* __restrict__ Ks,
                                               const float* __restrict__ bg,
                                               const float* __restrict__ p,
                                               float* __restrict__ a_out,
                                               float* __restrict__ part,
                                               const float* __restrict__ errpart) {
    if (is_done(errpart)) return;
    __shared__ float bsw[NN];        // 32 KB, swizzled so row-pass reads are conflict-free
    __shared__ float arow[32];
    __shared__ float rowhalf[8][2];
    const int t = threadIdx.x;
    const int w = t >> 6, lane = t & 63;
    const int band = blockIdx.x * 32;

    // stage b into swizzled LDS: float col c at [ (c>>10)*1024 + ((c>>2)&3)*256 + ((c>>4)&63)*4 + (c&3) ]
    {
        float4 g0 = ((const float4*)bg)[2 * t];
        float4 g1 = ((const float4*)bg)[2 * t + 1];
        float vals[8] = {g0.x, g0.y, g0.z, g0.w, g1.x, g1.y, g1.z, g1.w};
        int c0 = t * 8;
#pragma unroll
        for (int u = 0; u < 8; ++u) {
            int c = c0 + u;
            bsw[(c >> 10) * 1024 + ((c >> 2) & 3) * 256 + ((c >> 4) & 63) * 4 + (c & 3)] = vals[u];
        }
    }
    __syncthreads();

    float cacc[8] = {0.f, 0.f, 0.f, 0.f, 0.f, 0.f, 0.f, 0.f};
    const float4* b4 = (const float4*)bsw;

    for (int sub = 0; sub < 4; ++sub) {
        // ---- row pass: wave w handles row (w>>1), half (w&1): 4096 cols ----
        const int rl = w >> 1, half = w & 1;
        const int rglob = band + sub * 8 + rl;
        const uint4* kp = (const uint4*)(Ks + (size_t)rglob * NN + half * 4096);
        float rs = 0.f;
#pragma unroll
        for (int c = 0; c < 4; ++c) {
            uint4 kv = kp[c * 64 + lane];
            const unsigned int* kw = (const unsigned int*)&kv;
            const int kc = half * 4 + c;
#pragma unroll
            for (int j4 = 0; j4 < 4; ++j4) {
                float kf[4];
                fp8x4_to_f32(kw[j4], kf);
                float4 bv = b4[(kc * 4 + j4) * 64 + lane];
                rs = fmaf(kf[0], bv.x, rs);
                rs = fmaf(kf[1], bv.y, rs);
                rs = fmaf(kf[2], bv.z, rs);
                rs = fmaf(kf[3], bv.w, rs);
            }
        }
#pragma unroll
        for (int off = 32; off > 0; off >>= 1) rs += __shfl_down(rs, off, 64);
        if (lane == 0) rowhalf[rl][half] = rs;
        __syncthreads();
        if (t < 8) {
            int rg = band + sub * 8 + t;
            float av = p[rg] / (rowhalf[t][0] + rowhalf[t][1]);
            arow[sub * 8 + t] = av;
            a_out[rg] = av;
        }
        __syncthreads();
        // ---- col pass: re-read sub-band (L2-hot); thread t owns cols [8t,8t+8) ----
        const uint2* kp2 = (const uint2*)(Ks + (size_t)(band + sub * 8) * NN);
#pragma unroll
        for (int r8 = 0; r8 < 8; ++r8) {
            uint2 kv = kp2[r8 * (NN / 8) + t];
            float kf[8];
            fp8x4_to_f32(kv.x, kf);
            fp8x4_to_f32(kv.y, kf + 4);
            float av = arow[sub * 8 + r8];
#pragma unroll
            for (int j = 0; j < 8; ++j) cacc[j] = fmaf(kf[j], av, cacc[j]);
        }
        // no barrier needed: next sub's rowhalf writes are ordered after this sub's barrier 2
    }
    float4* pp = (float4*)(part + (size_t)blockIdx.x * NN + t * 8);
    pp[0] = make_float4(cacc[0], cacc[1], cacc[2], cacc[3]);
    pp[1] = make_float4(cacc[4], cacc[5], cacc[6], cacc[7]);
}

// ---- finalize b: sum 256 partials per col; deterministic err partials ----
__global__ __launch_bounds__(256) void k_div(const float* __restrict__ part,
                                             const float* __restrict__ q,
                                             float* __restrict__ b,
                                             float* __restrict__ errpart) {
    if (is_done(errpart)) return;            // keep frozen state intact
    const int t = threadIdx.x;
    const int c = t & 31, ibc = t >> 5;      // grid 256: 32 cols/WG, 8 chunk-rows
    const int col = blockIdx.x * 32 + c;
    float s = 0.f;
#pragma unroll 4
    for (int i = 0; i < 32; ++i) s += part[(size_t)(ibc * 32 + i) * NN + col];
    __shared__ float red[8][32];
    __shared__ float esc[32];
    red[ibc][c] = s;
    __syncthreads();
    if (ibc == 0) {
        float sum = 0.f;
#pragma unroll
        for (int k = 0; k < 8; ++k) sum += red[k][c];
        float bn = q[col] / sum;
        float d = bn - b[col];
        b[col] = bn;
        esc[c] = d * d;
    }
    __syncthreads();
    if (t == 0) {
        float e = 0.f;
#pragma unroll
        for (int k = 0; k < 32; ++k) e += esc[k];
        errpart[blockIdx.x] = e;
    }
}

// ---- final: T = a*Ks*b (scale-invariant), w = sum T*C, C from log2(Ks) ----
__global__ __launch_bounds__(256) void k_final(const unsigned char* __restrict__ Ks,
                                               const float* __restrict__ a,
                                               const float* __restrict__ b,
                                               float* __restrict__ out) {
    const int t = threadIdx.x;
    const int row = blockIdx.x;              // grid 8192
    const float ai = a[row];
    const uint2* kp = (const uint2*)(Ks + (size_t)row * NN);
    float* Trow = out + 1 + (size_t)row * NN;
    float w = 0.f;
    const float c1 = EPSF * LN2F;
#pragma unroll
    for (int k = 0; k < 4; ++k) {
        const int col = k * 2048 + t * 8;
        uint2 kv = kp[k * 256 + t];
        float kf[8];
        fp8x4_to_f32(kv.x, kf);
        fp8x4_to_f32(kv.y, kf + 4);
        float4 b0 = *(const float4*)(b + col);
        float4 b1 = *(const float4*)(b + col + 4);
        float bv[8] = {b0.x, b0.y, b0.z, b0.w, b1.x, b1.y, b1.z, b1.w};
#pragma unroll
        for (int j = 0; j < 8; ++j) {
            float ks = kf[j];
            float Tv = ai * ks * bv[j];
            float Cv = c1 * (KLOG2 - __builtin_amdgcn_logf(fmaxf(ks, 1e-35f)));
            w = fmaf(Tv, Cv, w);
            Trow[col + j] = Tv;              // d_out+1: scalar stores (offset 4B)
        }
    }
#pragma unroll
    for (int off = 32; off > 0; off >>= 1) w += __shfl_down(w, off, 64);
    __shared__ float red[4];
    if ((t & 63) == 0) red[t >> 6] = w;
    __syncthreads();
    if (t == 0) atomicAdd(out, (red[0] + red[1]) + (red[2] + red[3]));
}

extern "C" void kernel_launch(void* const* d_in, const int* in_sizes, int n_in,
                              void* d_out, int out_size, void* d_ws, size_t ws_size,
                              hipStream_t stream) {
    const float* x = (const float*)d_in[0];
    const float* y = (const float*)d_in[1];
    const float* p = (const float*)d_in[2];
    const float* q = (const float*)d_in[3];
    float* out = (float*)d_out;
    if (ws_size < WS_NEEDED) return;
    char* ws = (char*)d_ws;
    unsigned char* Ks = (unsigned char*)(ws + OFF_KS);
    float* part = (float*)(ws + OFF_PART);
    float* a = (float*)(ws + OFF_A);
    float* b = (float*)(ws + OFF_B);
    float* x2 = (float*)(ws + OFF_X2);
    float* y2 = (float*)(ws + OFF_Y2);
    float* errpart = (float*)(ws + OFF_ERR);

    k_init<<<dim3(32), dim3(256), 0, stream>>>(x, y, x2, y2, b, errpart, out);
    k_build<<<dim3(8192), dim3(256), 0, stream>>>(x, y, x2, y2, Ks);
    for (int it = 0; it < 50; ++it) {
        k_iter<<<dim3(256), dim3(1024), 0, stream>>>(Ks, b, p, a, part, errpart);
        k_div<<<dim3(256), dim3(256), 0, stream>>>(part, q, b, errpart);
    }
    k_final<<<dim3(8192), dim3(256), 0, stream>>>(Ks, a, b, out);
}